// Round 4
// baseline (43285.464 us; speedup 1.0000x reference)
//
#include <hip/hip_runtime.h>
#include <hip/hip_bf16.h>
#include <float.h>
#include <math.h>

#define HEADS 16
#define HD 64
#define DIM 1024
#define NTOK 4096
#define QKVN 3072

// ---------------------------------------------------------------------------
// GEMM: C[M][N] = A[M][K] @ B[K][N], fp32, row-major, optional ReLU.
// 64x64 tile, BK=16, 256 threads, 4x4 microtile. (Round-1 audited code.)
// ---------------------------------------------------------------------------
template <int RELU>
__global__ __launch_bounds__(256) void gemm_nn(const float* __restrict__ A,
                                               const float* __restrict__ B,
                                               float* __restrict__ C,
                                               int M, int N, int K) {
  __shared__ float As[16][68];
  __shared__ float Bs[16][68];
  const int t = threadIdx.x;
  const int row0 = blockIdx.y * 64;
  const int col0 = blockIdx.x * 64;
  const int tm = t & 15;
  const int tn = t >> 4;
  const int ar = t >> 2;
  const int ak = (t & 3) * 4;
  const int bk = t >> 4;
  const int bc = (t & 15) * 4;

  float acc[4][4] = {};

  for (int k0 = 0; k0 < K; k0 += 16) {
    float4 a4 = *(const float4*)(A + (size_t)(row0 + ar) * K + k0 + ak);
    float4 b4 = *(const float4*)(B + (size_t)(k0 + bk) * N + col0 + bc);
    __syncthreads();
    As[ak + 0][ar] = a4.x;
    As[ak + 1][ar] = a4.y;
    As[ak + 2][ar] = a4.z;
    As[ak + 3][ar] = a4.w;
    *(float4*)&Bs[bk][bc] = b4;
    __syncthreads();
#pragma unroll
    for (int kk = 0; kk < 16; ++kk) {
      float4 av = *(const float4*)&As[kk][tm * 4];
      float4 bv = *(const float4*)&Bs[kk][tn * 4];
      float a_[4] = {av.x, av.y, av.z, av.w};
      float b_[4] = {bv.x, bv.y, bv.z, bv.w};
#pragma unroll
      for (int ii = 0; ii < 4; ++ii)
#pragma unroll
        for (int jj = 0; jj < 4; ++jj) acc[ii][jj] += a_[ii] * b_[jj];
    }
  }

#pragma unroll
  for (int ii = 0; ii < 4; ++ii) {
    float4 o4 = make_float4(acc[ii][0], acc[ii][1], acc[ii][2], acc[ii][3]);
    if (RELU) {
      o4.x = fmaxf(o4.x, 0.f);
      o4.y = fmaxf(o4.y, 0.f);
      o4.z = fmaxf(o4.z, 0.f);
      o4.w = fmaxf(o4.w, 0.f);
    }
    *(float4*)(C + (size_t)(row0 + tm * 4 + ii) * N + col0 + tn * 4) = o4;
  }
}

// ---------------------------------------------------------------------------
// RoPE in-place on fp32 qkv [NTOK][3072], fp64 table math.
// Block = one token (4096 blocks x 512 threads: h = t>>5, j = t&31).
// Reference: out[j] = t[j]*cos(i*invf_j) - t[j+32]*sin(i*invf_j)
//            out[j+32] = t[j+32]*cos + t[j]*sin,  invf_j = 10000^(-j/32).
// ---------------------------------------------------------------------------
__global__ __launch_bounds__(512) void rope64_kernel(float* __restrict__ qkv) {
  const int i = blockIdx.x;   // token
  const int t = threadIdx.x;  // 0..511
  const int h = t >> 5, j = t & 31;
  const double inv = pow(10000.0, -(double)j / 32.0);
  double sd, cd;
  sincos((double)i * inv, &sd, &cd);
  const float cc = (float)cd, ss = (float)sd;
  const size_t base = (size_t)i * QKVN + h * HD + j;
  float qa = qkv[base], qb = qkv[base + 32];
  qkv[base] = qa * cc - qb * ss;
  qkv[base + 32] = qb * cc + qa * ss;
  float ka = qkv[base + DIM], kb = qkv[base + DIM + 32];
  qkv[base + DIM] = ka * cc - kb * ss;
  qkv[base + DIM + 32] = kb * cc + ka * ss;
}

// ---------------------------------------------------------------------------
// Causal attention, exact two-pass softmax, fp32 VALU only.
// Grid = 1024 blocks: h = bid&15, q-block qb = 63-(bid>>4) (LPT), 64 rows.
// Block = 256 threads = 4 waves; wave w owns rows q0+w*16 .. +15.
// Per (row, tile): lane = key index in tile; pass 1 accumulates row max,
// pass 2 recomputes scores, p = expf(s - M), accumulates L and O (lane = dim).
// K LDS stride 69 (69 % 32 = 5, coprime: lane-private rows conflict-free).
// ---------------------------------------------------------------------------
__global__ __launch_bounds__(256) void attn2p(const float* __restrict__ qkv,
                                              float* __restrict__ att) {
  __shared__ float Q[64][68];
  __shared__ float Kt[64][69];
  __shared__ float Vt[64][69];
  __shared__ float Ps[4][64];
  const int bid = blockIdx.x;
  const int h = bid & 15;
  const int qb = 63 - (bid >> 4);  // 0..63, biggest-first
  const int q0 = qb * 64;
  const int t = threadIdx.x, w = t >> 6, lane = t & 63;

  // stage Q (fp32): row = t>>2, 16 cols per thread
  {
    const int r = t >> 2, c0 = (t & 3) * 16;
#pragma unroll
    for (int c = 0; c < 16; c += 4)
      *(float4*)&Q[r][c0 + c] =
          *(const float4*)(qkv + (size_t)(q0 + r) * QKVN + h * HD + c0 + c);
  }

  float M[16], L[16], O[16];
#pragma unroll
  for (int r = 0; r < 16; ++r) { M[r] = -FLT_MAX; L[r] = 0.f; O[r] = 0.f; }

  const int ntile = qb + 1;

  // ---- PASS 1: exact row max ----
  for (int tile = 0; tile < ntile; ++tile) {
    const int kv0 = tile * 64;
    __syncthreads();
    {  // stage K tile (scalar stores: stride 69 not 16B-aligned for float4)
      const int r = t >> 2, c0 = (t & 3) * 16;
      const float* kb = qkv + (size_t)(kv0 + r) * QKVN + DIM + h * HD + c0;
#pragma unroll
      for (int c = 0; c < 16; ++c) Kt[r][c0 + c] = kb[c];
    }
    __syncthreads();
#pragma unroll
    for (int r = 0; r < 16; ++r) {
      const int row = q0 + w * 16 + r;
      const int j = kv0 + lane;
      float s = -FLT_MAX;
      if (j <= row) {
        float acc = 0.f;
#pragma unroll
        for (int d = 0; d < 64; ++d) acc += Q[w * 16 + r][d] * Kt[lane][d];
        s = acc * 0.125f;
      }
      float mx = s;
#pragma unroll
      for (int off = 32; off > 0; off >>= 1) mx = fmaxf(mx, __shfl_xor(mx, off));
      M[r] = fmaxf(M[r], mx);
    }
  }

  // ---- PASS 2: recompute scores, exp, accumulate L and O ----
  for (int tile = 0; tile < ntile; ++tile) {
    const int kv0 = tile * 64;
    __syncthreads();
    {  // stage K and V tiles
      const int r = t >> 2, c0 = (t & 3) * 16;
      const float* kb = qkv + (size_t)(kv0 + r) * QKVN + DIM + h * HD + c0;
      const float* vb = kb + DIM;
#pragma unroll
      for (int c = 0; c < 16; ++c) {
        Kt[r][c0 + c] = kb[c];
        Vt[r][c0 + c] = vb[c];
      }
    }
    __syncthreads();
#pragma unroll
    for (int r = 0; r < 16; ++r) {
      const int row = q0 + w * 16 + r;
      const int j = kv0 + lane;
      float p = 0.f;
      if (j <= row) {
        float acc = 0.f;
#pragma unroll
        for (int d = 0; d < 64; ++d) acc += Q[w * 16 + r][d] * Kt[lane][d];
        p = expf(acc * 0.125f - M[r]);
      }
      float sum = p;
#pragma unroll
      for (int off = 32; off > 0; off >>= 1) sum += __shfl_xor(sum, off);
      L[r] += sum;
      Ps[w][lane] = p;  // same-wave DS write->read: in-order DS pipe
      float o = 0.f;
#pragma unroll
      for (int jj = 0; jj < 64; ++jj) o += Ps[w][jj] * Vt[jj][lane];
      O[r] += o;
    }
  }

  // write att: row = q0 + w*16 + r, col = h*64 + lane
#pragma unroll
  for (int r = 0; r < 16; ++r)
    att[(size_t)(q0 + w * 16 + r) * DIM + h * HD + lane] = O[r] / L[r];
}

// ---------------------------------------------------------------------------
// LayerNorm over last dim (1024), fp32 in/out, gamma fp32.
// ---------------------------------------------------------------------------
__global__ __launch_bounds__(256) void layernorm_kernel(const float* __restrict__ x,
                                                        const float* __restrict__ gamma,
                                                        float* __restrict__ out) {
  const int row = blockIdx.x;
  const int t = threadIdx.x;
  const float4 v = ((const float4*)(x + (size_t)row * DIM))[t];
  float s = v.x + v.y + v.z + v.w;
  float ss = v.x * v.x + v.y * v.y + v.z * v.z + v.w * v.w;
#pragma unroll
  for (int off = 32; off > 0; off >>= 1) {
    s += __shfl_xor(s, off);
    ss += __shfl_xor(ss, off);
  }
  __shared__ float red[8];
  const int wave = t >> 6, lane = t & 63;
  if (lane == 0) {
    red[wave] = s;
    red[4 + wave] = ss;
  }
  __syncthreads();
  const float S = red[0] + red[1] + red[2] + red[3];
  const float SS = red[4] + red[5] + red[6] + red[7];
  const float mean = S * (1.f / 1024.f);
  const float var = SS * (1.f / 1024.f) - mean * mean;
  const float r = rsqrtf(var + 1e-5f);
  const float4 g4 = ((const float4*)gamma)[t];
  float4 o;
  o.x = (v.x - mean) * r * g4.x;
  o.y = (v.y - mean) * r * g4.y;
  o.z = (v.z - mean) * r * g4.z;
  o.w = (v.w - mean) * r * g4.w;
  ((float4*)(out + (size_t)row * DIM))[t] = o;
}

// ---------------------------------------------------------------------------
extern "C" void kernel_launch(void* const* d_in, const int* in_sizes, int n_in,
                              void* d_out, int out_size, void* d_ws, size_t ws_size,
                              hipStream_t stream) {
  const float* x = (const float*)d_in[0];      // fp32 [4096][1024]
  const float* Wqkv = (const float*)d_in[1];   // fp32 [1024][3072]
  const float* Wo1 = (const float*)d_in[2];    // fp32 [1024][1024]
  const float* Wo2 = (const float*)d_in[3];    // fp32 [1024][1024]
  const float* gamma = (const float*)d_in[4];  // fp32 [1024]
  float* out = (float*)d_out;                  // fp32 [4096][1024]

  char* wsb = (char*)d_ws;
  // workspace (bytes), peak 50,331,648:
  //   qkv f32 [4096][3072] @ 0           (50,331,648)  dead after attention
  //   h1  f32 [4096][1024] @ 0           (reuse qkv region)
  //   h2  f32 [4096][1024] @ 16,777,216
  //   att f32 [4096][1024] -> lives in d_out (overwritten by final LN)
  float* qkv = (float*)wsb;
  float* h1 = (float*)wsb;
  float* h2 = (float*)(wsb + 16777216ull);
  float* att = out;

  // 1. qkv = x @ W_qkv
  gemm_nn<0><<<dim3(QKVN / 64, NTOK / 64), 256, 0, stream>>>(x, Wqkv, qkv, NTOK, QKVN, DIM);
  // 2. RoPE in-place (fp64 table math)
  rope64_kernel<<<NTOK, 512, 0, stream>>>(qkv);
  // 3. causal attention (exact two-pass softmax) -> att (in d_out)
  attn2p<<<NTOK / 64 * HEADS, 256, 0, stream>>>(qkv, att);
  // 4. h1 = relu(att @ W_o1)
  gemm_nn<1><<<dim3(DIM / 64, NTOK / 64), 256, 0, stream>>>(att, Wo1, h1, NTOK, DIM, DIM);
  // 5. h2 = h1 @ W_o2
  gemm_nn<0><<<dim3(DIM / 64, NTOK / 64), 256, 0, stream>>>(h1, Wo2, h2, NTOK, DIM, DIM);
  // 6. layernorm -> out (overwrites att scratch)
  layernorm_kernel<<<NTOK, 256, 0, stream>>>(h2, gamma, out);
}

// Round 5
// 811.028 us; speedup vs baseline: 53.3711x; 53.3711x over previous
//
#include <hip/hip_runtime.h>
#include <hip/hip_bf16.h>
#include <float.h>
#include <math.h>

#define HEADS 16
#define HD 64
#define DIM 1024
#define NTOK 4096
#define QKVN 3072

typedef short s8v __attribute__((ext_vector_type(8)));   // 8 bf16 bit-patterns (4 VGPR)
typedef float f4v __attribute__((ext_vector_type(4)));   // MFMA accumulator

static __device__ __forceinline__ unsigned short f2b(float f) {
  __hip_bfloat16 h = __float2bfloat16(f);
  unsigned short u;
  __builtin_memcpy(&u, &h, 2);
  return u;
}
static __device__ __forceinline__ s8v pack_bf8(float4 a, float4 b) {
  s8v r;
  r[0] = (short)f2b(a.x); r[1] = (short)f2b(a.y); r[2] = (short)f2b(a.z); r[3] = (short)f2b(a.w);
  r[4] = (short)f2b(b.x); r[5] = (short)f2b(b.y); r[6] = (short)f2b(b.z); r[7] = (short)f2b(b.w);
  return r;
}

// ---------------------------------------------------------------------------
// GEMM: C[M][N] = A[M][K] @ B[K][N], fp32, row-major, optional ReLU.
// 64x64 tile, BK=16, 256 threads, 4x4 microtile. (Validated round 4.)
// ---------------------------------------------------------------------------
template <int RELU>
__global__ __launch_bounds__(256) void gemm_nn(const float* __restrict__ A,
                                               const float* __restrict__ B,
                                               float* __restrict__ C,
                                               int M, int N, int K) {
  __shared__ float As[16][68];
  __shared__ float Bs[16][68];
  const int t = threadIdx.x;
  const int row0 = blockIdx.y * 64;
  const int col0 = blockIdx.x * 64;
  const int tm = t & 15;
  const int tn = t >> 4;
  const int ar = t >> 2;
  const int ak = (t & 3) * 4;
  const int bk = t >> 4;
  const int bc = (t & 15) * 4;

  float acc[4][4] = {};

  for (int k0 = 0; k0 < K; k0 += 16) {
    float4 a4 = *(const float4*)(A + (size_t)(row0 + ar) * K + k0 + ak);
    float4 b4 = *(const float4*)(B + (size_t)(k0 + bk) * N + col0 + bc);
    __syncthreads();
    As[ak + 0][ar] = a4.x;
    As[ak + 1][ar] = a4.y;
    As[ak + 2][ar] = a4.z;
    As[ak + 3][ar] = a4.w;
    *(float4*)&Bs[bk][bc] = b4;
    __syncthreads();
#pragma unroll
    for (int kk = 0; kk < 16; ++kk) {
      float4 av = *(const float4*)&As[kk][tm * 4];
      float4 bv = *(const float4*)&Bs[kk][tn * 4];
      float a_[4] = {av.x, av.y, av.z, av.w};
      float b_[4] = {bv.x, bv.y, bv.z, bv.w};
#pragma unroll
      for (int ii = 0; ii < 4; ++ii)
#pragma unroll
        for (int jj = 0; jj < 4; ++jj) acc[ii][jj] += a_[ii] * b_[jj];
    }
  }

#pragma unroll
  for (int ii = 0; ii < 4; ++ii) {
    float4 o4 = make_float4(acc[ii][0], acc[ii][1], acc[ii][2], acc[ii][3]);
    if (RELU) {
      o4.x = fmaxf(o4.x, 0.f);
      o4.y = fmaxf(o4.y, 0.f);
      o4.z = fmaxf(o4.z, 0.f);
      o4.w = fmaxf(o4.w, 0.f);
    }
    *(float4*)(C + (size_t)(row0 + tm * 4 + ii) * N + col0 + tn * 4) = o4;
  }
}

// ---------------------------------------------------------------------------
// RoPE in-place on fp32 qkv [NTOK][3072], fp64 table math. (Validated round 4;
// fp32 sincosf on large args is suspected cause of rounds-1/3 failure.)
// ---------------------------------------------------------------------------
__global__ __launch_bounds__(512) void rope64_kernel(float* __restrict__ qkv) {
  const int i = blockIdx.x;   // token
  const int t = threadIdx.x;  // 0..511
  const int h = t >> 5, j = t & 31;
  const double inv = pow(10000.0, -(double)j / 32.0);
  double sd, cd;
  sincos((double)i * inv, &sd, &cd);
  const float cc = (float)cd, ss = (float)sd;
  const size_t base = (size_t)i * QKVN + h * HD + j;
  float qa = qkv[base], qb = qkv[base + 32];
  qkv[base] = qa * cc - qb * ss;
  qkv[base + 32] = qb * cc + qa * ss;
  float ka = qkv[base + DIM], kb = qkv[base + DIM + 32];
  qkv[base + DIM] = ka * cc - kb * ss;
  qkv[base + DIM + 32] = kb * cc + ka * ss;
}

// ---------------------------------------------------------------------------
// MFMA flash attention (causal), fp32 qkv in, fp32 att out.
// Block = 4 waves = 64 q-rows of one head; wave w owns 16 q-rows.
// KV tiles of 64 staged in LDS as bf16 (K row-major, V transposed).
// S = QK^T via mfma_16x16x32_bf16 (C-frag: row = 4g+r, col = n*16+c);
// online softmax on C-frags (16-lane shfl row reductions); P -> wave-private
// LDS -> A-frags for PV. Frag layouts per m89/m92-verified mapping.
// ---------------------------------------------------------------------------
__global__ __launch_bounds__(256) void attn_mfma(const float* __restrict__ qkv,
                                                 float* __restrict__ att) {
  __shared__ unsigned short Ks[64][72];
  __shared__ unsigned short Vt[64][72];
  __shared__ unsigned short Pl[4][16][72];
  const int bid = blockIdx.x;
  const int h = bid & 15;
  const int qi = 63 - (bid >> 4);  // biggest-first (LPT)
  const int t = threadIdx.x;
  const int w = t >> 6, lane = t & 63;
  const int g = lane >> 4, c = lane & 15;
  const int q0 = qi * 64 + w * 16;

  // Q fragments: row = lane&15 (q0+c), k = kf*32 + g*8 + j
  s8v qf[2];
  {
    const float* qp = qkv + (size_t)(q0 + c) * QKVN + h * HD;
#pragma unroll
    for (int kf = 0; kf < 2; ++kf) {
      float4 f0 = *(const float4*)(qp + kf * 32 + g * 8);
      float4 f1 = *(const float4*)(qp + kf * 32 + g * 8 + 4);
      qf[kf] = pack_bf8(f0, f1);
    }
  }

  f4v O[4] = {};
  float mrow[4], lrow[4];
#pragma unroll
  for (int r = 0; r < 4; ++r) { mrow[r] = -1e30f; lrow[r] = 0.f; }

  const int ntile = qi + 1;
  for (int tile = 0; tile < ntile; ++tile) {
    const int kv0 = tile * 64;
    __syncthreads();
    // --- stage K (cast fp32 -> bf16, row-major) ---
    {
      const int ch = t & 15, kr0 = t >> 4;
#pragma unroll
      for (int it = 0; it < 4; ++it) {
        const int kr = kr0 + it * 16;
        float4 f = *(const float4*)(qkv + (size_t)(kv0 + kr) * QKVN + DIM + h * HD + ch * 4);
        ushort4 u;
        u.x = f2b(f.x); u.y = f2b(f.y); u.z = f2b(f.z); u.w = f2b(f.w);
        *(ushort4*)&Ks[kr][ch * 4] = u;
      }
      // --- stage V transposed: Vt[d][kv_local] ---
      const int kg = t & 15, dc = t >> 4;
      const float* vb = qkv + (size_t)(kv0 + 4 * kg) * QKVN + 2 * DIM + h * HD + dc * 4;
      float4 v0 = *(const float4*)(vb);
      float4 v1 = *(const float4*)(vb + QKVN);
      float4 v2 = *(const float4*)(vb + 2 * QKVN);
      float4 v3 = *(const float4*)(vb + 3 * QKVN);
      const float* r0 = (const float*)&v0;
      const float* r1 = (const float*)&v1;
      const float* r2 = (const float*)&v2;
      const float* r3 = (const float*)&v3;
#pragma unroll
      for (int dl = 0; dl < 4; ++dl) {
        ushort4 u;
        u.x = f2b(r0[dl]); u.y = f2b(r1[dl]); u.z = f2b(r2[dl]); u.w = f2b(r3[dl]);
        *(ushort4*)&Vt[dc * 4 + dl][kg * 4] = u;
      }
    }
    __syncthreads();

    // --- S = Q K^T ---
    f4v S[4] = {};
#pragma unroll
    for (int n = 0; n < 4; ++n)
#pragma unroll
      for (int kf = 0; kf < 2; ++kf) {
        s8v kfr = *(const s8v*)&Ks[n * 16 + c][kf * 32 + g * 8];
        S[n] = __builtin_amdgcn_mfma_f32_16x16x32_bf16(qf[kf], kfr, S[n], 0, 0, 0);
      }

    // --- scale + causal mask + row max (rows live on 16-lane c-groups) ---
    float rmax[4] = {-1e30f, -1e30f, -1e30f, -1e30f};
#pragma unroll
    for (int n = 0; n < 4; ++n)
#pragma unroll
      for (int r = 0; r < 4; ++r) {
        float s = S[n][r] * 0.125f;
        const int col = kv0 + n * 16 + c;
        const int row = q0 + 4 * g + r;
        s = (col > row) ? -1e30f : s;
        S[n][r] = s;
        rmax[r] = fmaxf(rmax[r], s);
      }
#pragma unroll
    for (int r = 0; r < 4; ++r) {
      rmax[r] = fmaxf(rmax[r], __shfl_xor(rmax[r], 1));
      rmax[r] = fmaxf(rmax[r], __shfl_xor(rmax[r], 2));
      rmax[r] = fmaxf(rmax[r], __shfl_xor(rmax[r], 4));
      rmax[r] = fmaxf(rmax[r], __shfl_xor(rmax[r], 8));
    }

    float corr[4], rsum[4] = {0.f, 0.f, 0.f, 0.f};
#pragma unroll
    for (int r = 0; r < 4; ++r) {
      const float mn = fmaxf(mrow[r], rmax[r]);
      corr[r] = __expf(mrow[r] - mn);
      mrow[r] = mn;
    }
    // --- P = exp(S - m) -> wave-private LDS (same-wave DS ordering) ---
#pragma unroll
    for (int n = 0; n < 4; ++n)
#pragma unroll
      for (int r = 0; r < 4; ++r) {
        const float p = __expf(S[n][r] - mrow[r]);
        rsum[r] += p;
        Pl[w][4 * g + r][n * 16 + c] = f2b(p);
      }
#pragma unroll
    for (int r = 0; r < 4; ++r) {
      rsum[r] += __shfl_xor(rsum[r], 1);
      rsum[r] += __shfl_xor(rsum[r], 2);
      rsum[r] += __shfl_xor(rsum[r], 4);
      rsum[r] += __shfl_xor(rsum[r], 8);
      lrow[r] = lrow[r] * corr[r] + rsum[r];
    }
#pragma unroll
    for (int n = 0; n < 4; ++n)
#pragma unroll
      for (int r = 0; r < 4; ++r) O[n][r] *= corr[r];

    // --- O += P V (A-frag rows = c from Pl; B-frag cols = d from Vt) ---
    s8v pf[2];
#pragma unroll
    for (int kf = 0; kf < 2; ++kf) pf[kf] = *(const s8v*)&Pl[w][c][kf * 32 + g * 8];
#pragma unroll
    for (int n = 0; n < 4; ++n)
#pragma unroll
      for (int kf = 0; kf < 2; ++kf) {
        s8v vf = *(const s8v*)&Vt[n * 16 + c][kf * 32 + g * 8];
        O[n] = __builtin_amdgcn_mfma_f32_16x16x32_bf16(pf[kf], vf, O[n], 0, 0, 0);
      }
  }

  // --- epilogue: normalize, store fp32 ---
  float inv[4];
#pragma unroll
  for (int r = 0; r < 4; ++r) inv[r] = 1.f / lrow[r];
#pragma unroll
  for (int n = 0; n < 4; ++n)
#pragma unroll
    for (int r = 0; r < 4; ++r) {
      const int row = q0 + 4 * g + r;
      att[(size_t)row * DIM + h * HD + n * 16 + c] = O[n][r] * inv[r];
    }
}

// ---------------------------------------------------------------------------
// LayerNorm over last dim (1024), fp32 in/out, gamma fp32. (Validated round 4.)
// ---------------------------------------------------------------------------
__global__ __launch_bounds__(256) void layernorm_kernel(const float* __restrict__ x,
                                                        const float* __restrict__ gamma,
                                                        float* __restrict__ out) {
  const int row = blockIdx.x;
  const int t = threadIdx.x;
  const float4 v = ((const float4*)(x + (size_t)row * DIM))[t];
  float s = v.x + v.y + v.z + v.w;
  float ss = v.x * v.x + v.y * v.y + v.z * v.z + v.w * v.w;
#pragma unroll
  for (int off = 32; off > 0; off >>= 1) {
    s += __shfl_xor(s, off);
    ss += __shfl_xor(ss, off);
  }
  __shared__ float red[8];
  const int wave = t >> 6, lane = t & 63;
  if (lane == 0) {
    red[wave] = s;
    red[4 + wave] = ss;
  }
  __syncthreads();
  const float S = red[0] + red[1] + red[2] + red[3];
  const float SS = red[4] + red[5] + red[6] + red[7];
  const float mean = S * (1.f / 1024.f);
  const float var = SS * (1.f / 1024.f) - mean * mean;
  const float r = rsqrtf(var + 1e-5f);
  const float4 g4 = ((const float4*)gamma)[t];
  float4 o;
  o.x = (v.x - mean) * r * g4.x;
  o.y = (v.y - mean) * r * g4.y;
  o.z = (v.z - mean) * r * g4.z;
  o.w = (v.w - mean) * r * g4.w;
  ((float4*)(out + (size_t)row * DIM))[t] = o;
}

// ---------------------------------------------------------------------------
extern "C" void kernel_launch(void* const* d_in, const int* in_sizes, int n_in,
                              void* d_out, int out_size, void* d_ws, size_t ws_size,
                              hipStream_t stream) {
  const float* x = (const float*)d_in[0];      // fp32 [4096][1024]
  const float* Wqkv = (const float*)d_in[1];   // fp32 [1024][3072]
  const float* Wo1 = (const float*)d_in[2];    // fp32 [1024][1024]
  const float* Wo2 = (const float*)d_in[3];    // fp32 [1024][1024]
  const float* gamma = (const float*)d_in[4];  // fp32 [1024]
  float* out = (float*)d_out;                  // fp32 [4096][1024]

  char* wsb = (char*)d_ws;
  // workspace (bytes), peak 50,331,648 (identical plan to round 4):
  //   qkv f32 [4096][3072] @ 0           (50,331,648)  dead after attention
  //   h1  f32 [4096][1024] @ 0           (reuse qkv region)
  //   h2  f32 [4096][1024] @ 16,777,216
  //   att f32 [4096][1024] -> lives in d_out (overwritten by final LN)
  float* qkv = (float*)wsb;
  float* h1 = (float*)wsb;
  float* h2 = (float*)(wsb + 16777216ull);
  float* att = out;

  // 1. qkv = x @ W_qkv
  gemm_nn<0><<<dim3(QKVN / 64, NTOK / 64), 256, 0, stream>>>(x, Wqkv, qkv, NTOK, QKVN, DIM);
  // 2. RoPE in-place (fp64 table math)
  rope64_kernel<<<NTOK, 512, 0, stream>>>(qkv);
  // 3. causal flash attention (bf16 MFMA) -> att (in d_out)
  attn_mfma<<<NTOK / 64 * HEADS, 256, 0, stream>>>(qkv, att);
  // 4. h1 = relu(att @ W_o1)
  gemm_nn<1><<<dim3(DIM / 64, NTOK / 64), 256, 0, stream>>>(att, Wo1, h1, NTOK, DIM, DIM);
  // 5. h2 = h1 @ W_o2
  gemm_nn<0><<<dim3(DIM / 64, NTOK / 64), 256, 0, stream>>>(h1, Wo2, h2, NTOK, DIM, DIM);
  // 6. layernorm -> out (overwrites att scratch)
  layernorm_kernel<<<NTOK, 256, 0, stream>>>(h2, gamma, out);
}

// Round 7
// 359.406 us; speedup vs baseline: 120.4362x; 2.2566x over previous
//
#include <hip/hip_runtime.h>
#include <hip/hip_bf16.h>
#include <float.h>
#include <math.h>

#define HEADS 16
#define HD 64
#define DIM 1024
#define NTOK 4096
#define QKVN 3072

typedef short s8v __attribute__((ext_vector_type(8)));   // 8 bf16 bit-patterns (4 VGPR)
typedef float f4v __attribute__((ext_vector_type(4)));   // MFMA accumulator

static __device__ __forceinline__ unsigned short f2b(float f) {
  __hip_bfloat16 h = __float2bfloat16(f);
  unsigned short u;
  __builtin_memcpy(&u, &h, 2);
  return u;
}
static __device__ __forceinline__ s8v pack_bf8(float4 a, float4 b) {
  s8v r;
  r[0] = (short)f2b(a.x); r[1] = (short)f2b(a.y); r[2] = (short)f2b(a.z); r[3] = (short)f2b(a.w);
  r[4] = (short)f2b(b.x); r[5] = (short)f2b(b.y); r[6] = (short)f2b(b.z); r[7] = (short)f2b(b.w);
  return r;
}

// ---------------------------------------------------------------------------
// Transpose + cast: fp32 [K][N] -> bf16 [N][K]. 32x32 tiles, 256 threads.
// ---------------------------------------------------------------------------
__global__ __launch_bounds__(256) void transpose_f2b(const float* __restrict__ in,
                                                     unsigned short* __restrict__ out,
                                                     int K, int N) {
  __shared__ unsigned short T[32][36];
  const int k0 = blockIdx.y * 32, n0 = blockIdx.x * 32;
  const int t = threadIdx.x;
  const int r = t >> 3, c4 = (t & 7) * 4;
  float4 f = *(const float4*)(in + (size_t)(k0 + r) * N + n0 + c4);
  T[r][c4 + 0] = f2b(f.x);
  T[r][c4 + 1] = f2b(f.y);
  T[r][c4 + 2] = f2b(f.z);
  T[r][c4 + 3] = f2b(f.w);
  __syncthreads();
  ushort4 o;
  o.x = T[c4 + 0][r];
  o.y = T[c4 + 1][r];
  o.z = T[c4 + 2][r];
  o.w = T[c4 + 3][r];
  *(ushort4*)(out + (size_t)(n0 + r) * K + k0 + c4) = o;
}

// ---------------------------------------------------------------------------
// GEMM: C[M][N] = A[M][K] (fp32, cast in staging) @ Bt[N][K]^T (bf16).
// 128x128 tile, BK=32, 4 waves (2x2 of 64x64), mfma_f32_16x16x32_bf16,
// 4x4 frags/wave. Fragment mappings identical to attn_mfma (validated R5).
// ---------------------------------------------------------------------------
template <int OUT_F32, int RELU>
__global__ __launch_bounds__(256) void gemm_bt(const float* __restrict__ A,
                                               const unsigned short* __restrict__ Bt,
                                               void* __restrict__ Cv,
                                               int M, int N, int K) {
  __shared__ unsigned short As[128][40];
  __shared__ unsigned short Bs[128][40];
  const int t = threadIdx.x;
  const int wave = t >> 6, lane = t & 63;
  const int wr = wave >> 1, wc = wave & 1;
  const int g = lane >> 4, c = lane & 15;
  const int m0 = blockIdx.y * 128, n0 = blockIdx.x * 128;

  const int sr = t >> 2;        // staging row 0..63 (and +64)
  const int sc = (t & 3) * 8;   // staging col (bf16 elems), 16B chunks

  f4v acc[4][4] = {};

  for (int k0 = 0; k0 < K; k0 += 32) {
    const float* p0 = A + (size_t)(m0 + sr) * K + k0 + sc;
    const float* p1 = A + (size_t)(m0 + sr + 64) * K + k0 + sc;
    s8v a0 = pack_bf8(*(const float4*)p0, *(const float4*)(p0 + 4));
    s8v a1 = pack_bf8(*(const float4*)p1, *(const float4*)(p1 + 4));
    s8v b0 = *(const s8v*)(Bt + (size_t)(n0 + sr) * K + k0 + sc);
    s8v b1 = *(const s8v*)(Bt + (size_t)(n0 + sr + 64) * K + k0 + sc);
    __syncthreads();  // previous iteration's frag reads done before overwrite
    *(s8v*)&As[sr][sc] = a0;
    *(s8v*)&As[sr + 64][sc] = a1;
    *(s8v*)&Bs[sr][sc] = b0;
    *(s8v*)&Bs[sr + 64][sc] = b1;
    __syncthreads();
    s8v af[4], bf[4];
#pragma unroll
    for (int m = 0; m < 4; ++m) af[m] = *(const s8v*)&As[wr * 64 + m * 16 + c][g * 8];
#pragma unroll
    for (int n = 0; n < 4; ++n) bf[n] = *(const s8v*)&Bs[wc * 64 + n * 16 + c][g * 8];
#pragma unroll
    for (int m = 0; m < 4; ++m)
#pragma unroll
      for (int n = 0; n < 4; ++n)
        acc[m][n] = __builtin_amdgcn_mfma_f32_16x16x32_bf16(af[m], bf[n], acc[m][n], 0, 0, 0);
  }

#pragma unroll
  for (int m = 0; m < 4; ++m)
#pragma unroll
    for (int n = 0; n < 4; ++n)
#pragma unroll
      for (int r = 0; r < 4; ++r) {
        const int row = m0 + wr * 64 + m * 16 + g * 4 + r;
        const int col = n0 + wc * 64 + n * 16 + c;
        float v = acc[m][n][r];
        if (RELU) v = fmaxf(v, 0.f);
        if (OUT_F32)
          ((float*)Cv)[(size_t)row * N + col] = v;
        else
          ((unsigned short*)Cv)[(size_t)row * N + col] = f2b(v);
      }
}

// ---------------------------------------------------------------------------
// RoPE in-place on bf16 qkv [NTOK][3072]. fp64 table math (R4-validated
// convention), computed once per token by 32 threads, shared via LDS.
// ---------------------------------------------------------------------------
__global__ __launch_bounds__(512) void rope64_kernel(unsigned short* __restrict__ qkv) {
  __shared__ float cs[32], sn[32];
  const int i = blockIdx.x;   // token
  const int t = threadIdx.x;  // 0..511
  if (t < 32) {
    const double inv = pow(10000.0, -(double)t / 32.0);
    double sd, cd;
    sincos((double)i * inv, &sd, &cd);
    cs[t] = (float)cd;
    sn[t] = (float)sd;
  }
  __syncthreads();
  const int h = t >> 5, j = t & 31;
  const float cc = cs[j], ss = sn[j];
  const size_t base = (size_t)i * QKVN + h * HD + j;
  const float qa = __bfloat162float(*(const __hip_bfloat16*)&qkv[base]);
  const float qb = __bfloat162float(*(const __hip_bfloat16*)&qkv[base + 32]);
  qkv[base] = f2b(qa * cc - qb * ss);
  qkv[base + 32] = f2b(qb * cc + qa * ss);
  const float ka = __bfloat162float(*(const __hip_bfloat16*)&qkv[base + DIM]);
  const float kb = __bfloat162float(*(const __hip_bfloat16*)&qkv[base + DIM + 32]);
  qkv[base + DIM] = f2b(ka * cc - kb * ss);
  qkv[base + DIM + 32] = f2b(kb * cc + ka * ss);
}

// ---------------------------------------------------------------------------
// MFMA flash attention (causal), bf16 qkv in, fp32 att out (R5-validated
// structure; staging is now a plain bf16 copy instead of fp32+cast).
// ---------------------------------------------------------------------------
__global__ __launch_bounds__(256) void attn_mfma(const unsigned short* __restrict__ qkv,
                                                 float* __restrict__ att) {
  __shared__ unsigned short Ks[64][72];
  __shared__ unsigned short Vt[64][72];
  __shared__ unsigned short Pl[4][16][72];
  const int bid = blockIdx.x;
  const int h = bid & 15;
  const int qi = 63 - (bid >> 4);  // biggest-first (LPT)
  const int t = threadIdx.x;
  const int w = t >> 6, lane = t & 63;
  const int g = lane >> 4, c = lane & 15;
  const int q0 = qi * 64 + w * 16;

  // Q fragments: row = lane&15 (q0+c), k = kf*32 + g*8 + j
  s8v qf[2];
#pragma unroll
  for (int kf = 0; kf < 2; ++kf)
    qf[kf] = *(const s8v*)(qkv + (size_t)(q0 + c) * QKVN + h * HD + kf * 32 + g * 8);

  f4v O[4] = {};
  float mrow[4], lrow[4];
#pragma unroll
  for (int r = 0; r < 4; ++r) { mrow[r] = -1e30f; lrow[r] = 0.f; }

  const int ntile = qi + 1;
  for (int tile = 0; tile < ntile; ++tile) {
    const int kv0 = tile * 64;
    __syncthreads();
    // --- stage K rows (plain bf16 copy, 16B chunks) ---
    {
      const int kr = t >> 3;        // 0..31
      const int kc = (t & 7) * 8;   // 0..56
#pragma unroll
      for (int it = 0; it < 2; ++it) {
        const int r = kr + it * 32;
        *(s8v*)&Ks[r][kc] =
            *(const s8v*)(qkv + (size_t)(kv0 + r) * QKVN + DIM + h * HD + kc);
      }
      // --- stage V transposed: Vt[d][kv_local], 4x4 block per thread ---
      const int kg = t & 15, dc = t >> 4;
      const unsigned short* vb = qkv + (size_t)(kv0 + 4 * kg) * QKVN + 2 * DIM + h * HD + dc * 4;
      ushort4 v0 = *(const ushort4*)(vb);
      ushort4 v1 = *(const ushort4*)(vb + QKVN);
      ushort4 v2 = *(const ushort4*)(vb + 2 * QKVN);
      ushort4 v3 = *(const ushort4*)(vb + 3 * QKVN);
      const unsigned short* r0 = (const unsigned short*)&v0;
      const unsigned short* r1 = (const unsigned short*)&v1;
      const unsigned short* r2 = (const unsigned short*)&v2;
      const unsigned short* r3 = (const unsigned short*)&v3;
#pragma unroll
      for (int dl = 0; dl < 4; ++dl) {
        ushort4 u;
        u.x = r0[dl]; u.y = r1[dl]; u.z = r2[dl]; u.w = r3[dl];
        *(ushort4*)&Vt[dc * 4 + dl][kg * 4] = u;
      }
    }
    __syncthreads();

    // --- S = Q K^T ---
    f4v S[4] = {};
#pragma unroll
    for (int n = 0; n < 4; ++n)
#pragma unroll
      for (int kf = 0; kf < 2; ++kf) {
        s8v kfr = *(const s8v*)&Ks[n * 16 + c][kf * 32 + g * 8];
        S[n] = __builtin_amdgcn_mfma_f32_16x16x32_bf16(qf[kf], kfr, S[n], 0, 0, 0);
      }

    // --- scale + causal mask + row max ---
    float rmax[4] = {-1e30f, -1e30f, -1e30f, -1e30f};
#pragma unroll
    for (int n = 0; n < 4; ++n)
#pragma unroll
      for (int r = 0; r < 4; ++r) {
        float s = S[n][r] * 0.125f;
        const int col = kv0 + n * 16 + c;
        const int row = q0 + 4 * g + r;
        s = (col > row) ? -1e30f : s;
        S[n][r] = s;
        rmax[r] = fmaxf(rmax[r], s);
      }
#pragma unroll
    for (int r = 0; r < 4; ++r) {
      rmax[r] = fmaxf(rmax[r], __shfl_xor(rmax[r], 1));
      rmax[r] = fmaxf(rmax[r], __shfl_xor(rmax[r], 2));
      rmax[r] = fmaxf(rmax[r], __shfl_xor(rmax[r], 4));
      rmax[r] = fmaxf(rmax[r], __shfl_xor(rmax[r], 8));
    }

    float corr[4], rsum[4] = {0.f, 0.f, 0.f, 0.f};
#pragma unroll
    for (int r = 0; r < 4; ++r) {
      const float mn = fmaxf(mrow[r], rmax[r]);
      corr[r] = __expf(mrow[r] - mn);
      mrow[r] = mn;
    }
    // --- P = exp(S - m) -> wave-private LDS ---
#pragma unroll
    for (int n = 0; n < 4; ++n)
#pragma unroll
      for (int r = 0; r < 4; ++r) {
        const float p = __expf(S[n][r] - mrow[r]);
        rsum[r] += p;
        Pl[w][4 * g + r][n * 16 + c] = f2b(p);
      }
#pragma unroll
    for (int r = 0; r < 4; ++r) {
      rsum[r] += __shfl_xor(rsum[r], 1);
      rsum[r] += __shfl_xor(rsum[r], 2);
      rsum[r] += __shfl_xor(rsum[r], 4);
      rsum[r] += __shfl_xor(rsum[r], 8);
      lrow[r] = lrow[r] * corr[r] + rsum[r];
    }
#pragma unroll
    for (int n = 0; n < 4; ++n)
#pragma unroll
      for (int r = 0; r < 4; ++r) O[n][r] *= corr[r];

    // --- O += P V ---
    s8v pf[2];
#pragma unroll
    for (int kf = 0; kf < 2; ++kf) pf[kf] = *(const s8v*)&Pl[w][c][kf * 32 + g * 8];
#pragma unroll
    for (int n = 0; n < 4; ++n)
#pragma unroll
      for (int kf = 0; kf < 2; ++kf) {
        s8v vf = *(const s8v*)&Vt[n * 16 + c][kf * 32 + g * 8];
        O[n] = __builtin_amdgcn_mfma_f32_16x16x32_bf16(pf[kf], vf, O[n], 0, 0, 0);
      }
  }

  // --- epilogue: normalize, store fp32 ---
  float inv[4];
#pragma unroll
  for (int r = 0; r < 4; ++r) inv[r] = 1.f / lrow[r];
#pragma unroll
  for (int n = 0; n < 4; ++n)
#pragma unroll
    for (int r = 0; r < 4; ++r) {
      const int row = q0 + 4 * g + r;
      att[(size_t)row * DIM + h * HD + n * 16 + c] = O[n][r] * inv[r];
    }
}

// ---------------------------------------------------------------------------
// LayerNorm over last dim (1024), fp32 in/out, gamma fp32. (Validated R4.)
// ---------------------------------------------------------------------------
__global__ __launch_bounds__(256) void layernorm_kernel(const float* __restrict__ x,
                                                        const float* __restrict__ gamma,
                                                        float* __restrict__ out) {
  const int row = blockIdx.x;
  const int t = threadIdx.x;
  const float4 v = ((const float4*)(x + (size_t)row * DIM))[t];
  float s = v.x + v.y + v.z + v.w;
  float ss = v.x * v.x + v.y * v.y + v.z * v.z + v.w * v.w;
#pragma unroll
  for (int off = 32; off > 0; off >>= 1) {
    s += __shfl_xor(s, off);
    ss += __shfl_xor(ss, off);
  }
  __shared__ float red[8];
  const int wave = t >> 6, lane = t & 63;
  if (lane == 0) {
    red[wave] = s;
    red[4 + wave] = ss;
  }
  __syncthreads();
  const float S = red[0] + red[1] + red[2] + red[3];
  const float SS = red[4] + red[5] + red[6] + red[7];
  const float mean = S * (1.f / 1024.f);
  const float var = SS * (1.f / 1024.f) - mean * mean;
  const float r = rsqrtf(var + 1e-5f);
  const float4 g4 = ((const float4*)gamma)[t];
  float4 o;
  o.x = (v.x - mean) * r * g4.x;
  o.y = (v.y - mean) * r * g4.y;
  o.z = (v.z - mean) * r * g4.z;
  o.w = (v.w - mean) * r * g4.w;
  ((float4*)(out + (size_t)row * DIM))[t] = o;
}

// ---------------------------------------------------------------------------
extern "C" void kernel_launch(void* const* d_in, const int* in_sizes, int n_in,
                              void* d_out, int out_size, void* d_ws, size_t ws_size,
                              hipStream_t stream) {
  const float* x = (const float*)d_in[0];      // fp32 [4096][1024]
  const float* Wqkv = (const float*)d_in[1];   // fp32 [1024][3072]
  const float* Wo1 = (const float*)d_in[2];    // fp32 [1024][1024]
  const float* Wo2 = (const float*)d_in[3];    // fp32 [1024][1024]
  const float* gamma = (const float*)d_in[4];  // fp32 [1024]
  float* out = (float*)d_out;                  // fp32 [4096][1024]

  char* wsb = (char*)d_ws;
  // workspace (bytes), peak 35,651,584 (< R4's validated 50.3 MB):
  //   qkv  bf16 [4096][3072] @ 0           (25,165,824)  dead after attn
  //   Wqkvt bf16 [3072][1024]@ 25,165,824  ( 6,291,456)  dead after QKV GEMM
  //   Wo1t  bf16 [1024][1024]@ 31,457,280  ( 2,097,152)  dead after o1 GEMM
  //   Wo2t  bf16 [1024][1024]@ 33,554,432  ( 2,097,152)
  //   att  f32 -> lives in d_out (consumed by o1, overwritten by LN)
  //   h1   f32 [4096][1024] @ 0            (reuse qkv region)
  //   h2   f32 [4096][1024] @ 16,777,216   (tail overlaps dead Wqkvt/Wo1t)
  unsigned short* qkv = (unsigned short*)wsb;
  unsigned short* Wqkvt = (unsigned short*)(wsb + 25165824ull);
  unsigned short* Wo1t = (unsigned short*)(wsb + 31457280ull);
  unsigned short* Wo2t = (unsigned short*)(wsb + 33554432ull);
  float* h1 = (float*)wsb;
  float* h2 = (float*)(wsb + 16777216ull);
  float* att = out;

  // 0. transpose+cast weights to bf16 [N][K]
  transpose_f2b<<<dim3(QKVN / 32, DIM / 32), 256, 0, stream>>>(Wqkv, Wqkvt, DIM, QKVN);
  transpose_f2b<<<dim3(DIM / 32, DIM / 32), 256, 0, stream>>>(Wo1, Wo1t, DIM, DIM);
  transpose_f2b<<<dim3(DIM / 32, DIM / 32), 256, 0, stream>>>(Wo2, Wo2t, DIM, DIM);
  // 1. qkv = x @ W_qkv  (bf16 out)
  gemm_bt<0, 0><<<dim3(QKVN / 128, NTOK / 128), 256, 0, stream>>>(x, Wqkvt, qkv, NTOK, QKVN, DIM);
  // 2. RoPE in-place on Q,K (bf16, fp64 LDS table)
  rope64_kernel<<<NTOK, 512, 0, stream>>>(qkv);
  // 3. causal flash attention (bf16 MFMA) -> att fp32 (in d_out)
  attn_mfma<<<NTOK / 64 * HEADS, 256, 0, stream>>>(qkv, att);
  // 4. h1 = relu(att @ W_o1)  (fp32 out)
  gemm_bt<1, 1><<<dim3(DIM / 128, NTOK / 128), 256, 0, stream>>>(att, Wo1t, h1, NTOK, DIM, DIM);
  // 5. h2 = h1 @ W_o2  (fp32 out)
  gemm_bt<1, 0><<<dim3(DIM / 128, NTOK / 128), 256, 0, stream>>>(h1, Wo2t, h2, NTOK, DIM, DIM);
  // 6. layernorm -> out (overwrites att scratch)
  layernorm_kernel<<<NTOK, 256, 0, stream>>>(h2, gamma, out);
}

// Round 8
// 343.636 us; speedup vs baseline: 125.9630x; 1.0459x over previous
//
#include <hip/hip_runtime.h>
#include <hip/hip_bf16.h>
#include <float.h>
#include <math.h>

#define HEADS 16
#define HD 64
#define DIM 1024
#define NTOK 4096
#define QKVN 3072

typedef short s8v __attribute__((ext_vector_type(8)));   // 8 bf16 bit-patterns (4 VGPR)
typedef float f4v __attribute__((ext_vector_type(4)));   // MFMA accumulator

static __device__ __forceinline__ unsigned short f2b(float f) {
  __hip_bfloat16 h = __float2bfloat16(f);
  unsigned short u;
  __builtin_memcpy(&u, &h, 2);
  return u;
}
static __device__ __forceinline__ s8v pack_bf8(float4 a, float4 b) {
  s8v r;
  r[0] = (short)f2b(a.x); r[1] = (short)f2b(a.y); r[2] = (short)f2b(a.z); r[3] = (short)f2b(a.w);
  r[4] = (short)f2b(b.x); r[5] = (short)f2b(b.y); r[6] = (short)f2b(b.z); r[7] = (short)f2b(b.w);
  return r;
}
// async global->LDS, 16B per lane (HW: wave-uniform base + lane*16)
static __device__ __forceinline__ void gload16(const unsigned short* g, unsigned short* l) {
  __builtin_amdgcn_global_load_lds(
      (const __attribute__((address_space(1))) void*)g,
      (__attribute__((address_space(3))) void*)l, 16, 0, 0);
}

// ---------------------------------------------------------------------------
// Cast fp32 -> bf16, 8 elems/thread.
// ---------------------------------------------------------------------------
__global__ __launch_bounds__(256) void cast_f2b(const float* __restrict__ in,
                                                unsigned short* __restrict__ out) {
  const int i = (blockIdx.x * 256 + threadIdx.x) * 8;
  float4 a = *(const float4*)(in + i);
  float4 b = *(const float4*)(in + i + 4);
  *(s8v*)(out + i) = pack_bf8(a, b);
}

// ---------------------------------------------------------------------------
// Transpose + cast: fp32 [K][N] -> bf16 [N][K]. 32x32 tiles, 256 threads.
// ---------------------------------------------------------------------------
__global__ __launch_bounds__(256) void transpose_f2b(const float* __restrict__ in,
                                                     unsigned short* __restrict__ out,
                                                     int K, int N) {
  __shared__ unsigned short T[32][36];
  const int k0 = blockIdx.y * 32, n0 = blockIdx.x * 32;
  const int t = threadIdx.x;
  const int r = t >> 3, c4 = (t & 7) * 4;
  float4 f = *(const float4*)(in + (size_t)(k0 + r) * N + n0 + c4);
  T[r][c4 + 0] = f2b(f.x);
  T[r][c4 + 1] = f2b(f.y);
  T[r][c4 + 2] = f2b(f.z);
  T[r][c4 + 3] = f2b(f.w);
  __syncthreads();
  ushort4 o;
  o.x = T[c4 + 0][r];
  o.y = T[c4 + 1][r];
  o.z = T[c4 + 2][r];
  o.w = T[c4 + 3][r];
  *(ushort4*)(out + (size_t)(n0 + r) * K + k0 + c4) = o;
}

// ---------------------------------------------------------------------------
// GEMM: C[M][N] = A[M][K] (bf16) @ Bt[N][K]^T (bf16). 128x128 tile, BK=32,
// 4 waves (2x2 of 64x64), mfma_f32_16x16x32_bf16, 4x4 frags/wave.
// m97 structure: LINEAR LDS [128][32] (conflict-free for b128 frag reads:
// bank spread uniform 8/bank = wave64 minimum) + global_load_lds width 16.
// LDS dest lane order: thread t writes row t>>2, cols (t&3)*8 -> linear t*16B.
// ---------------------------------------------------------------------------
template <int OUT_F32, int RELU>
__global__ __launch_bounds__(256) void gemm_bb(const unsigned short* __restrict__ A,
                                               const unsigned short* __restrict__ Bt,
                                               void* __restrict__ Cv,
                                               int M, int N, int K) {
  __shared__ __align__(16) unsigned short As[128 * 32];
  __shared__ __align__(16) unsigned short Bs[128 * 32];
  const int t = threadIdx.x;
  const int wave = t >> 6, lane = t & 63;
  const int wr = wave >> 1, wc = wave & 1;
  const int g = lane >> 4, c = lane & 15;
  const int m0 = blockIdx.y * 128, n0 = blockIdx.x * 128;

  const int sr = t >> 2;        // staging row 0..63 (and +64)
  const int sc = (t & 3) * 8;   // staging col (bf16 elems), 16B chunks

  const unsigned short* a0p = A + (size_t)(m0 + sr) * K + sc;
  const unsigned short* a1p = A + (size_t)(m0 + sr + 64) * K + sc;
  const unsigned short* b0p = Bt + (size_t)(n0 + sr) * K + sc;
  const unsigned short* b1p = Bt + (size_t)(n0 + sr + 64) * K + sc;
  unsigned short* lA0 = As + t * 8;
  unsigned short* lA1 = As + 2048 + t * 8;
  unsigned short* lB0 = Bs + t * 8;
  unsigned short* lB1 = Bs + 2048 + t * 8;

  f4v acc[4][4] = {};

  for (int k0 = 0; k0 < K; k0 += 32) {
    __syncthreads();  // previous iteration's frag reads done before overwrite
    gload16(a0p + k0, lA0);
    gload16(a1p + k0, lA1);
    gload16(b0p + k0, lB0);
    gload16(b1p + k0, lB1);
    __syncthreads();  // compiler drains vmcnt before barrier -> LDS valid
    s8v af[4], bf[4];
#pragma unroll
    for (int m = 0; m < 4; ++m) af[m] = *(const s8v*)&As[(wr * 64 + m * 16 + c) * 32 + g * 8];
#pragma unroll
    for (int n = 0; n < 4; ++n) bf[n] = *(const s8v*)&Bs[(wc * 64 + n * 16 + c) * 32 + g * 8];
#pragma unroll
    for (int m = 0; m < 4; ++m)
#pragma unroll
      for (int n = 0; n < 4; ++n)
        acc[m][n] = __builtin_amdgcn_mfma_f32_16x16x32_bf16(af[m], bf[n], acc[m][n], 0, 0, 0);
  }

#pragma unroll
  for (int m = 0; m < 4; ++m)
#pragma unroll
    for (int n = 0; n < 4; ++n)
#pragma unroll
      for (int r = 0; r < 4; ++r) {
        const int row = m0 + wr * 64 + m * 16 + g * 4 + r;
        const int col = n0 + wc * 64 + n * 16 + c;
        float v = acc[m][n][r];
        if (RELU) v = fmaxf(v, 0.f);
        if (OUT_F32)
          ((float*)Cv)[(size_t)row * N + col] = v;
        else
          ((unsigned short*)Cv)[(size_t)row * N + col] = f2b(v);
      }
}

// ---------------------------------------------------------------------------
// RoPE in-place on bf16 qkv [NTOK][3072]. fp64 table (validated convention).
// NEW: Q section pre-scaled by 0.125 (exact in bf16) so attention skips the
// per-element scale.
// ---------------------------------------------------------------------------
__global__ __launch_bounds__(512) void rope64_kernel(unsigned short* __restrict__ qkv) {
  __shared__ float cs[32], sn[32];
  const int i = blockIdx.x;   // token
  const int t = threadIdx.x;  // 0..511
  if (t < 32) {
    const double inv = pow(10000.0, -(double)t / 32.0);
    double sd, cd;
    sincos((double)i * inv, &sd, &cd);
    cs[t] = (float)cd;
    sn[t] = (float)sd;
  }
  __syncthreads();
  const int h = t >> 5, j = t & 31;
  const float cc = cs[j], ss = sn[j];
  const size_t base = (size_t)i * QKVN + h * HD + j;
  const float qa = __bfloat162float(*(const __hip_bfloat16*)&qkv[base]);
  const float qb = __bfloat162float(*(const __hip_bfloat16*)&qkv[base + 32]);
  qkv[base] = f2b((qa * cc - qb * ss) * 0.125f);
  qkv[base + 32] = f2b((qb * cc + qa * ss) * 0.125f);
  const float ka = __bfloat162float(*(const __hip_bfloat16*)&qkv[base + DIM]);
  const float kb = __bfloat162float(*(const __hip_bfloat16*)&qkv[base + DIM + 32]);
  qkv[base + DIM] = f2b(ka * cc - kb * ss);
  qkv[base + DIM + 32] = f2b(kb * cc + ka * ss);
}

// ---------------------------------------------------------------------------
// MFMA flash attention (causal), bf16 qkv in, bf16 att out.
// R5/R7-validated structure + this round: (a) scale pre-folded into Q,
// (b) causal mask only on the last tile (wave-uniform), (c) defer-max
// rescale with THR=8 (T13): rescale only when rmax > mrow+8 anywhere.
// ---------------------------------------------------------------------------
__global__ __launch_bounds__(256) void attn_mfma(const unsigned short* __restrict__ qkv,
                                                 unsigned short* __restrict__ att) {
  __shared__ unsigned short Ks[64][72];
  __shared__ unsigned short Vt[64][72];
  __shared__ unsigned short Pl[4][16][72];
  const int bid = blockIdx.x;
  const int h = bid & 15;
  const int qi = 63 - (bid >> 4);  // biggest-first (LPT)
  const int t = threadIdx.x;
  const int w = t >> 6, lane = t & 63;
  const int g = lane >> 4, c = lane & 15;
  const int q0 = qi * 64 + w * 16;

  // Q fragments: row = lane&15 (q0+c), k = kf*32 + g*8 + j (pre-scaled)
  s8v qf[2];
#pragma unroll
  for (int kf = 0; kf < 2; ++kf)
    qf[kf] = *(const s8v*)(qkv + (size_t)(q0 + c) * QKVN + h * HD + kf * 32 + g * 8);

  f4v O[4] = {};
  float mrow[4], lrow[4];
#pragma unroll
  for (int r = 0; r < 4; ++r) { mrow[r] = -1e30f; lrow[r] = 0.f; }

  const int ntile = qi + 1;
  for (int tile = 0; tile < ntile; ++tile) {
    const int kv0 = tile * 64;
    __syncthreads();
    // --- stage K rows (plain bf16 copy, 16B chunks) ---
    {
      const int kr = t >> 3;        // 0..31
      const int kc = (t & 7) * 8;   // 0..56
#pragma unroll
      for (int it = 0; it < 2; ++it) {
        const int r = kr + it * 32;
        *(s8v*)&Ks[r][kc] =
            *(const s8v*)(qkv + (size_t)(kv0 + r) * QKVN + DIM + h * HD + kc);
      }
      // --- stage V transposed: Vt[d][kv_local], 4x4 block per thread ---
      const int kg = t & 15, dc = t >> 4;
      const unsigned short* vb = qkv + (size_t)(kv0 + 4 * kg) * QKVN + 2 * DIM + h * HD + dc * 4;
      ushort4 v0 = *(const ushort4*)(vb);
      ushort4 v1 = *(const ushort4*)(vb + QKVN);
      ushort4 v2 = *(const ushort4*)(vb + 2 * QKVN);
      ushort4 v3 = *(const ushort4*)(vb + 3 * QKVN);
      const unsigned short* r0 = (const unsigned short*)&v0;
      const unsigned short* r1 = (const unsigned short*)&v1;
      const unsigned short* r2 = (const unsigned short*)&v2;
      const unsigned short* r3 = (const unsigned short*)&v3;
#pragma unroll
      for (int dl = 0; dl < 4; ++dl) {
        ushort4 u;
        u.x = r0[dl]; u.y = r1[dl]; u.z = r2[dl]; u.w = r3[dl];
        *(ushort4*)&Vt[dc * 4 + dl][kg * 4] = u;
      }
    }
    __syncthreads();

    // --- S = Q K^T (scale pre-folded into Q) ---
    f4v S[4] = {};
#pragma unroll
    for (int n = 0; n < 4; ++n)
#pragma unroll
      for (int kf = 0; kf < 2; ++kf) {
        s8v kfr = *(const s8v*)&Ks[n * 16 + c][kf * 32 + g * 8];
        S[n] = __builtin_amdgcn_mfma_f32_16x16x32_bf16(qf[kf], kfr, S[n], 0, 0, 0);
      }

    // --- causal mask (only the last tile can cross the diagonal) + row max ---
    float rmax[4] = {-1e30f, -1e30f, -1e30f, -1e30f};
    if (kv0 + 63 > q0) {
#pragma unroll
      for (int n = 0; n < 4; ++n)
#pragma unroll
        for (int r = 0; r < 4; ++r) {
          float s = S[n][r];
          const int col = kv0 + n * 16 + c;
          const int row = q0 + 4 * g + r;
          s = (col > row) ? -1e30f : s;
          S[n][r] = s;
          rmax[r] = fmaxf(rmax[r], s);
        }
    } else {
#pragma unroll
      for (int n = 0; n < 4; ++n)
#pragma unroll
        for (int r = 0; r < 4; ++r) rmax[r] = fmaxf(rmax[r], S[n][r]);
    }
#pragma unroll
    for (int r = 0; r < 4; ++r) {
      rmax[r] = fmaxf(rmax[r], __shfl_xor(rmax[r], 1));
      rmax[r] = fmaxf(rmax[r], __shfl_xor(rmax[r], 2));
      rmax[r] = fmaxf(rmax[r], __shfl_xor(rmax[r], 4));
      rmax[r] = fmaxf(rmax[r], __shfl_xor(rmax[r], 8));
    }

    // --- defer-max (T13, THR=8): rescale only on significant max growth ---
    bool upd = false;
#pragma unroll
    for (int r = 0; r < 4; ++r) upd = upd || (rmax[r] > mrow[r] + 8.0f);
    if (__any((int)upd)) {
#pragma unroll
      for (int r = 0; r < 4; ++r) {
        const float mn = fmaxf(mrow[r], rmax[r]);
        const float corr = __expf(mrow[r] - mn);
        mrow[r] = mn;
        lrow[r] *= corr;
#pragma unroll
        for (int n = 0; n < 4; ++n) O[n][r] *= corr;
      }
    }
    // --- P = exp(S - m) (bounded by e^8) -> wave-private LDS ---
    float rsum[4] = {0.f, 0.f, 0.f, 0.f};
#pragma unroll
    for (int n = 0; n < 4; ++n)
#pragma unroll
      for (int r = 0; r < 4; ++r) {
        const float p = __expf(S[n][r] - mrow[r]);
        rsum[r] += p;
        Pl[w][4 * g + r][n * 16 + c] = f2b(p);
      }
#pragma unroll
    for (int r = 0; r < 4; ++r) {
      rsum[r] += __shfl_xor(rsum[r], 1);
      rsum[r] += __shfl_xor(rsum[r], 2);
      rsum[r] += __shfl_xor(rsum[r], 4);
      rsum[r] += __shfl_xor(rsum[r], 8);
      lrow[r] += rsum[r];
    }

    // --- O += P V ---
    s8v pf[2];
#pragma unroll
    for (int kf = 0; kf < 2; ++kf) pf[kf] = *(const s8v*)&Pl[w][c][kf * 32 + g * 8];
#pragma unroll
    for (int n = 0; n < 4; ++n)
#pragma unroll
      for (int kf = 0; kf < 2; ++kf) {
        s8v vf = *(const s8v*)&Vt[n * 16 + c][kf * 32 + g * 8];
        O[n] = __builtin_amdgcn_mfma_f32_16x16x32_bf16(pf[kf], vf, O[n], 0, 0, 0);
      }
  }

  // --- epilogue: normalize, store bf16 ---
  float inv[4];
#pragma unroll
  for (int r = 0; r < 4; ++r) inv[r] = 1.f / lrow[r];
#pragma unroll
  for (int n = 0; n < 4; ++n)
#pragma unroll
    for (int r = 0; r < 4; ++r) {
      const int row = q0 + 4 * g + r;
      att[(size_t)row * DIM + h * HD + n * 16 + c] = f2b(O[n][r] * inv[r]);
    }
}

// ---------------------------------------------------------------------------
// LayerNorm over last dim (1024), fp32 in/out, gamma fp32. (Validated R4.)
// ---------------------------------------------------------------------------
__global__ __launch_bounds__(256) void layernorm_kernel(const float* __restrict__ x,
                                                        const float* __restrict__ gamma,
                                                        float* __restrict__ out) {
  const int row = blockIdx.x;
  const int t = threadIdx.x;
  const float4 v = ((const float4*)(x + (size_t)row * DIM))[t];
  float s = v.x + v.y + v.z + v.w;
  float ss = v.x * v.x + v.y * v.y + v.z * v.z + v.w * v.w;
#pragma unroll
  for (int off = 32; off > 0; off >>= 1) {
    s += __shfl_xor(s, off);
    ss += __shfl_xor(ss, off);
  }
  __shared__ float red[8];
  const int wave = t >> 6, lane = t & 63;
  if (lane == 0) {
    red[wave] = s;
    red[4 + wave] = ss;
  }
  __syncthreads();
  const float S = red[0] + red[1] + red[2] + red[3];
  const float SS = red[4] + red[5] + red[6] + red[7];
  const float mean = S * (1.f / 1024.f);
  const float var = SS * (1.f / 1024.f) - mean * mean;
  const float r = rsqrtf(var + 1e-5f);
  const float4 g4 = ((const float4*)gamma)[t];
  float4 o;
  o.x = (v.x - mean) * r * g4.x;
  o.y = (v.y - mean) * r * g4.y;
  o.z = (v.z - mean) * r * g4.z;
  o.w = (v.w - mean) * r * g4.w;
  ((float4*)(out + (size_t)row * DIM))[t] = o;
}

// ---------------------------------------------------------------------------
extern "C" void kernel_launch(void* const* d_in, const int* in_sizes, int n_in,
                              void* d_out, int out_size, void* d_ws, size_t ws_size,
                              hipStream_t stream) {
  const float* x = (const float*)d_in[0];      // fp32 [4096][1024]
  const float* Wqkv = (const float*)d_in[1];   // fp32 [1024][3072]
  const float* Wo1 = (const float*)d_in[2];    // fp32 [1024][1024]
  const float* Wo2 = (const float*)d_in[3];    // fp32 [1024][1024]
  const float* gamma = (const float*)d_in[4];  // fp32 [1024]
  float* out = (float*)d_out;                  // fp32 [4096][1024]

  char* wsb = (char*)d_ws;
  // workspace (bytes), peak 44,040,192:
  //   xb   bf16 [4096][1024] @ 0           ( 8,388,608)  dead after QKV GEMM
  //   qkv  bf16 [4096][3072] @ 8,388,608   (25,165,824)  dead after attn
  //   Wqkvt bf16 [3072][1024]@ 33,554,432  ( 6,291,456)  dead after QKV GEMM
  //   Wo1t  bf16 [1024][1024]@ 39,845,888  ( 2,097,152)
  //   Wo2t  bf16 [1024][1024]@ 41,943,040  ( 2,097,152)
  //   att  bf16 [4096][1024] @ 0           (reuse xb region)
  //   h1   bf16 [4096][1024] @ 8,388,608   (reuse qkv region)
  //   h2   f32  [4096][1024] @ 16,777,216  (reuse qkv region tail)
  unsigned short* xb = (unsigned short*)wsb;
  unsigned short* qkv = (unsigned short*)(wsb + 8388608ull);
  unsigned short* Wqkvt = (unsigned short*)(wsb + 33554432ull);
  unsigned short* Wo1t = (unsigned short*)(wsb + 39845888ull);
  unsigned short* Wo2t = (unsigned short*)(wsb + 41943040ull);
  unsigned short* att = (unsigned short*)wsb;
  unsigned short* h1 = (unsigned short*)(wsb + 8388608ull);
  float* h2 = (float*)(wsb + 16777216ull);

  // 0. casts: x -> bf16; weights -> bf16 [N][K]
  cast_f2b<<<NTOK * DIM / (256 * 8), 256, 0, stream>>>(x, xb);
  transpose_f2b<<<dim3(QKVN / 32, DIM / 32), 256, 0, stream>>>(Wqkv, Wqkvt, DIM, QKVN);
  transpose_f2b<<<dim3(DIM / 32, DIM / 32), 256, 0, stream>>>(Wo1, Wo1t, DIM, DIM);
  transpose_f2b<<<dim3(DIM / 32, DIM / 32), 256, 0, stream>>>(Wo2, Wo2t, DIM, DIM);
  // 1. qkv = xb @ W_qkv  (bf16 out)
  gemm_bb<0, 0><<<dim3(QKVN / 128, NTOK / 128), 256, 0, stream>>>(xb, Wqkvt, qkv, NTOK, QKVN, DIM);
  // 2. RoPE in-place on Q,K (Q pre-scaled by 1/8)
  rope64_kernel<<<NTOK, 512, 0, stream>>>(qkv);
  // 3. causal flash attention -> att bf16
  attn_mfma<<<NTOK / 64 * HEADS, 256, 0, stream>>>(qkv, att);
  // 4. h1 = relu(att @ W_o1)  (bf16 out)
  gemm_bb<0, 1><<<dim3(DIM / 128, NTOK / 128), 256, 0, stream>>>(att, Wo1t, h1, NTOK, DIM, DIM);
  // 5. h2 = h1 @ W_o2  (fp32 out)
  gemm_bb<1, 0><<<dim3(DIM / 128, NTOK / 128), 256, 0, stream>>>(h1, Wo2t, h2, NTOK, DIM, DIM);
  // 6. layernorm -> out
  layernorm_kernel<<<NTOK, 256, 0, stream>>>(h2, gamma, out);
}